// Round 9
// baseline (660.127 us; speedup 1.0000x reference)
//
#include <hip/hip_runtime.h>
#include <hip/hip_bf16.h>

typedef __bf16 bf16x8 __attribute__((ext_vector_type(8)));
typedef float f32x4 __attribute__((ext_vector_type(4)));

#define D 128
#define H 256
#define TM 32
#define THREADS 256
#define LN_EPS 1e-5f
#define NSCAN 50176            // 49 * 1024 >= num_nodes (50000)

// ---------------------------------------------------------------------------
// Pack w1 [128x256], w2 [256x256], wo [256x128] (f32 row-major, K x N) into
// bf16 MFMA-fragment-contiguous blocks:
//   out[b*512 + l*8 + i] = W[(k0 + (l>>4)*8 + i) * N + n0 + (l&15)]
//   block id: b = (n0/16)*(K/32) + (k0/32)
// ---------------------------------------------------------------------------
__global__ void pack_weights(const float* __restrict__ w1,
                             const float* __restrict__ w2,
                             const float* __restrict__ wo,
                             __bf16* __restrict__ pw) {
    int tid = blockIdx.x * blockDim.x + threadIdx.x;
    const float* W; int K, NN, local;
    if (tid < 32768)       { W = w1; K = 128; NN = 256; local = tid; }
    else if (tid < 98304)  { W = w2; K = 256; NN = 256; local = tid - 32768; }
    else if (tid < 131072) { W = wo; K = 256; NN = 128; local = tid - 98304; }
    else return;
    int b = local >> 9, within = local & 511;
    int l = within >> 3, i = within & 7;
    int nbk = K >> 5;
    int n0 = (b / nbk) << 4, k0 = (b % nbk) << 5;
    int k = k0 + ((l >> 4) << 3) + i;
    int n = n0 + (l & 15);
    pw[tid] = (__bf16)W[k * NN + n];
}

__global__ void zero_out_kernel(float4* __restrict__ out, int n4) {
    int i = blockIdx.x * blockDim.x + threadIdx.x;
    if (i < n4) out[i] = float4{0.f, 0.f, 0.f, 0.f};
}

// ------------------------------ CSR build ----------------------------------
__global__ void csr_zero_counts(int* __restrict__ counts) {
    int i = blockIdx.x * blockDim.x + threadIdx.x;
    if (i < NSCAN) counts[i] = 0;
}

__global__ void csr_hist(const int* __restrict__ eidx, int* __restrict__ counts,
                         int* __restrict__ pos, int E) {
    int e = blockIdx.x * blockDim.x + threadIdx.x;
    if (e < E) pos[e] = atomicAdd(&counts[eidx[e]], 1);
}

// 49 blocks x 256 threads x 4 elems: per-block exclusive scan + block totals
__global__ void csr_scan1(const int* __restrict__ counts, int* __restrict__ offs,
                          int* __restrict__ bsum) {
    __shared__ int wsum[4];
    int tid = threadIdx.x, blk = blockIdx.x;
    int base = blk * 1024 + tid * 4;
    int c0 = counts[base], c1 = counts[base+1], c2 = counts[base+2], c3 = counts[base+3];
    int tot = c0 + c1 + c2 + c3;
    int lane = tid & 63, wv = tid >> 6;
    int inc = tot;
    #pragma unroll
    for (int d = 1; d < 64; d <<= 1) {
        int v = __shfl_up(inc, d);
        if (lane >= d) inc += v;
    }
    if (lane == 63) wsum[wv] = inc;
    __syncthreads();
    int wbase = 0;
    for (int w = 0; w < wv; ++w) wbase += wsum[w];
    int excl = wbase + inc - tot;
    offs[base]   = excl;
    offs[base+1] = excl + c0;
    offs[base+2] = excl + c0 + c1;
    offs[base+3] = excl + c0 + c1 + c2;
    if (tid == 255) bsum[blk] = wbase + inc;
}

__global__ void csr_scan2(int* __restrict__ bsum) {   // in-place exclusive, 49 elems
    int l = threadIdx.x;                              // 64 threads
    int v = (l < 49) ? bsum[l] : 0;
    int inc = v;
    #pragma unroll
    for (int d = 1; d < 64; d <<= 1) {
        int u = __shfl_up(inc, d);
        if (l >= d) inc += u;
    }
    if (l < 49) bsum[l] = inc - v;
}

__global__ void csr_scan3(int* __restrict__ offs, const int* __restrict__ bsum) {
    int i = blockIdx.x * blockDim.x + threadIdx.x;
    if (i < NSCAN) offs[i] += bsum[i >> 10];
}

__global__ void csr_place(const int* __restrict__ eidx, const int* __restrict__ offs,
                          const int* __restrict__ pos, int* __restrict__ order, int E) {
    int e = blockIdx.x * blockDim.x + threadIdx.x;
    if (e < E) order[offs[eidx[e]] + pos[e]] = e;
}

// ------------------------------ gather -------------------------------------
// One wave per node: sum ~12 per-edge rows (512B coalesced reads), plain store.
// Zero atomics; per-node sum in fixed (CSR) order -> deterministic output.
__global__ __launch_bounds__(256) void gather_kernel(
    const float* __restrict__ eout, const int* __restrict__ offs,
    const int* __restrict__ order, float* __restrict__ out, int N) {
    int wave = threadIdx.x >> 6, lane = threadIdx.x & 63;
    int n = blockIdx.x * 4 + wave;
    if (n >= N) return;
    int beg = offs[n];
    int end = offs[n + 1];          // offs[N] == E (pad counts are zero)
    float ax = 0.f, ay = 0.f;
    for (int j = beg; j < end; ++j) {
        int e = order[j];
        const float2 v = *reinterpret_cast<const float2*>(eout + (size_t)e * D + lane * 2);
        ax += v.x; ay += v.y;
    }
    *reinterpret_cast<float2*>(out + (size_t)n * D + lane * 2) = float2{ax, ay};
}

// ---------------------------------------------------------------------------
// Fused edge MLP (R4-proven structure: all-bf16 GEMMs, 7 barriers, TM=32).
// R8 lessons: (a) atomics were NOT the bottleneck (438us either way) — keep
// CSR/eout for determinism; (b) expm1f cost +20pts VALUBusy (33.7->54%) —
// back to __expf(x)-1 (error ~1e-7, R4-proven); (c) occupancy model:
// waves/SIMD = 512/(archVGPR + accVGPR); R8 was 84+48=132 -> 3 blocks/CU.
// Target arch<=80 so 128 total -> 4 blocks/CU; launch_bounds (256,4).
// LDS: sA (8 KB) aliases prefix of sH (16 KB); last sA read (GEMM1, pre-bar2)
// is 2 barriers before first sH write (post-bar3) — proven safe R4/R7/R8.
// ---------------------------------------------------------------------------
__global__ __launch_bounds__(THREADS, 4) void fused_edge_kernel(
    const float* __restrict__ edges, const int* __restrict__ eidx,
    const float* __restrict__ ln1_g, const float* __restrict__ ln1_b,
    const float* __restrict__ b1,
    const float* __restrict__ ln2_g, const float* __restrict__ ln2_b,
    const float* __restrict__ b2,
    const float* __restrict__ wg, const float* __restrict__ bg,
    const float* __restrict__ bo,
    const __bf16* __restrict__ pw,
    float* __restrict__ out, float* __restrict__ eout, int use_eout, int E)
{
    __shared__ __bf16 sH[TM * H];       // 16 KB; low 8 KB doubles as sA
    __shared__ float sRedS[4][TM];
    __shared__ float sRedQ[4][TM];
    __shared__ float sMu[TM], sRs[TM], sGate[TM];
    __shared__ int   sIdx[TM];
    __bf16* sA = sH;                    // alias (see header comment)

    const __bf16* pw1 = pw;             // 32768: w1 fragments
    const __bf16* pw2 = pw + 32768;     // 65536: w2 fragments
    const __bf16* pwo = pw + 98304;     // 32768: wo fragments

    const int t    = threadIdx.x;
    const int lane = t & 63;
    const int wave = t >> 6;
    const int lr   = lane & 15;         // tile row/col within 16
    const int lg   = lane >> 4;         // k-group / row-quad id
    const int e0   = blockIdx.x * TM;

    if (!use_eout && t < TM) sIdx[t] = (e0 + t < E) ? eidx[e0 + t] : 0;

    // ---------------- Phase 1: load edges + LN1 -> sA (bf16, swizzled) ------
    {
        const int row = t >> 3;          // 0..31
        const int c8  = t & 7;           // 16-col chunk of the row
        const int er  = min(e0 + row, E - 1);
        const float* src = edges + (size_t)er * D + c8 * 16;
        float x[16];
        #pragma unroll
        for (int i = 0; i < 4; ++i) {
            float4 v = reinterpret_cast<const float4*>(src)[i];
            x[i*4+0]=v.x; x[i*4+1]=v.y; x[i*4+2]=v.z; x[i*4+3]=v.w;
        }
        float s = 0.f, sq = 0.f;
        #pragma unroll
        for (int i = 0; i < 16; ++i) { s += x[i]; sq += x[i]*x[i]; }
        s  += __shfl_xor(s, 1);  s  += __shfl_xor(s, 2);  s  += __shfl_xor(s, 4);
        sq += __shfl_xor(sq, 1); sq += __shfl_xor(sq, 2); sq += __shfl_xor(sq, 4);
        const float mu  = s * (1.0f / D);
        const float var = sq * (1.0f / D) - mu * mu;
        const float rs  = rsqrtf(var + LN_EPS);
        #pragma unroll
        for (int i = 0; i < 2; ++i) {
            bf16x8 yv;
            #pragma unroll
            for (int j = 0; j < 8; ++j) {
                int c0 = c8*16 + i*8 + j;
                yv[j] = (__bf16)((x[i*8+j] - mu) * rs * ln1_g[c0] + ln1_b[c0]);
            }
            int idx = (row * D + c8*16 + i*8) ^ ((row & 7) << 3);
            *reinterpret_cast<bf16x8*>(&sA[idx]) = yv;
        }
    }
    __syncthreads();                                           // ---- bar1

    // ---------------- Phase 2: GEMM1  [32x128] x [128x256] ------------------
    f32x4 acc[2][4];
    #pragma unroll
    for (int a = 0; a < 2; ++a)
        #pragma unroll
        for (int b = 0; b < 4; ++b) acc[a][b] = f32x4{0.f,0.f,0.f,0.f};

    #pragma unroll
    for (int ks = 0; ks < 4; ++ks) {                 // k0 = ks*32
        bf16x8 af[2];
        #pragma unroll
        for (int mt = 0; mt < 2; ++mt) {
            int row = mt*16 + lr;
            int idx = (row * D + ks*32 + lg*8) ^ ((row & 7) << 3);
            af[mt] = *reinterpret_cast<const bf16x8*>(&sA[idx]);
        }
        bf16x8 bv[4];
        #pragma unroll
        for (int nt = 0; nt < 4; ++nt) {
            int blk = (wave*4 + nt) * 4 + ks;        // ctile*(128/32)+ks
            bv[nt] = *reinterpret_cast<const bf16x8*>(pw1 + blk*512 + lane*8);
        }
        #pragma unroll
        for (int mt = 0; mt < 2; ++mt)
            #pragma unroll
            for (int nt = 0; nt < 4; ++nt)
                acc[mt][nt] = __builtin_amdgcn_mfma_f32_16x16x32_bf16(af[mt], bv[nt], acc[mt][nt], 0, 0, 0);
    }

    // ---------------- Phase 3: +b1, ELU(expf-1), LN2 stats partials ---------
    float b1v[4];
    #pragma unroll
    for (int nt = 0; nt < 4; ++nt) b1v[nt] = b1[wave*64 + nt*16 + lr];
    {
        float ps[2][4], pq[2][4];                    // [mt][r]
        #pragma unroll
        for (int mt = 0; mt < 2; ++mt)
            #pragma unroll
            for (int r = 0; r < 4; ++r) { ps[mt][r] = 0.f; pq[mt][r] = 0.f; }
        #pragma unroll
        for (int mt = 0; mt < 2; ++mt)
            #pragma unroll
            for (int nt = 0; nt < 4; ++nt)
                #pragma unroll
                for (int r = 0; r < 4; ++r) {
                    float x = acc[mt][nt][r] + b1v[nt];
                    x = x > 0.f ? x : (__expf(x) - 1.0f);    // ELU (R4-proven; expm1f cost +20pts VALU)
                    acc[mt][nt][r] = x;
                    ps[mt][r] += x;
                    pq[mt][r] += x * x;
                }
        #pragma unroll
        for (int mt = 0; mt < 2; ++mt)
            #pragma unroll
            for (int r = 0; r < 4; ++r) {
                float s = ps[mt][r], q = pq[mt][r];
                s += __shfl_xor(s, 1); s += __shfl_xor(s, 2); s += __shfl_xor(s, 4); s += __shfl_xor(s, 8);
                q += __shfl_xor(q, 1); q += __shfl_xor(q, 2); q += __shfl_xor(q, 4); q += __shfl_xor(q, 8);
                if (lr == 0) {
                    int row = mt*16 + lg*4 + r;
                    sRedS[wave][row] = s;
                    sRedQ[wave][row] = q;
                }
            }
    }
    __syncthreads();                                           // ---- bar2
    if (t < TM) {
        float S = sRedS[0][t] + sRedS[1][t] + sRedS[2][t] + sRedS[3][t];
        float Q = sRedQ[0][t] + sRedQ[1][t] + sRedQ[2][t] + sRedQ[3][t];
        float mu  = S * (1.0f / H);
        float var = Q * (1.0f / H) - mu * mu;
        sMu[t] = mu;
        sRs[t] = rsqrtf(var + LN_EPS);
    }
    __syncthreads();                                           // ---- bar3

    // write LN2 output (bf16, swizzled) into sH (overwrites dead sA alias)
    {
        float g2v[4], bt2[4];
        #pragma unroll
        for (int nt = 0; nt < 4; ++nt) {
            g2v[nt] = ln2_g[wave*64 + nt*16 + lr];
            bt2[nt] = ln2_b[wave*64 + nt*16 + lr];
        }
        #pragma unroll
        for (int mt = 0; mt < 2; ++mt)
            #pragma unroll
            for (int r = 0; r < 4; ++r) {
                int row = mt*16 + lg*4 + r;
                float mu = sMu[row], rs = sRs[row];
                #pragma unroll
                for (int nt = 0; nt < 4; ++nt) {
                    int col = wave*64 + nt*16 + lr;
                    float h = (acc[mt][nt][r] - mu) * rs * g2v[nt] + bt2[nt];
                    int idx = (row * H + col) ^ ((row & 7) << 3);
                    sH[idx] = (__bf16)h;
                }
            }
    }
    __syncthreads();                                           // ---- bar4

    // ---------------- Phase 4: GEMM2  [32x256] x [256x256] ------------------
    #pragma unroll
    for (int a = 0; a < 2; ++a)
        #pragma unroll
        for (int b = 0; b < 4; ++b) acc[a][b] = f32x4{0.f,0.f,0.f,0.f};

    #pragma unroll
    for (int ks = 0; ks < 8; ++ks) {
        bf16x8 af[2];
        #pragma unroll
        for (int mt = 0; mt < 2; ++mt) {
            int row = mt*16 + lr;
            int idx = (row * H + ks*32 + lg*8) ^ ((row & 7) << 3);
            af[mt] = *reinterpret_cast<const bf16x8*>(&sH[idx]);
        }
        bf16x8 bv[4];
        #pragma unroll
        for (int nt = 0; nt < 4; ++nt) {
            int blk = (wave*4 + nt) * 8 + ks;        // ctile*(256/32)+ks
            bv[nt] = *reinterpret_cast<const bf16x8*>(pw2 + blk*512 + lane*8);
        }
        #pragma unroll
        for (int mt = 0; mt < 2; ++mt)
            #pragma unroll
            for (int nt = 0; nt < 4; ++nt)
                acc[mt][nt] = __builtin_amdgcn_mfma_f32_16x16x32_bf16(af[mt], bv[nt], acc[mt][nt], 0, 0, 0);
    }

    // ---------------- Phase 5: +b2, gate partials ---------------------------
    float pg[2][4];
    {
        float b2v[4], wgv[4];
        #pragma unroll
        for (int nt = 0; nt < 4; ++nt) {
            b2v[nt] = b2[wave*64 + nt*16 + lr];
            wgv[nt] = wg[wave*64 + nt*16 + lr];
        }
        #pragma unroll
        for (int mt = 0; mt < 2; ++mt)
            #pragma unroll
            for (int r = 0; r < 4; ++r) pg[mt][r] = 0.f;
        #pragma unroll
        for (int mt = 0; mt < 2; ++mt)
            #pragma unroll
            for (int nt = 0; nt < 4; ++nt)
                #pragma unroll
                for (int r = 0; r < 4; ++r) {
                    float h2 = acc[mt][nt][r] + b2v[nt];
                    acc[mt][nt][r] = h2;
                    pg[mt][r] += h2 * wgv[nt];
                }
        #pragma unroll
        for (int mt = 0; mt < 2; ++mt)
            #pragma unroll
            for (int r = 0; r < 4; ++r) {
                float s = pg[mt][r];
                s += __shfl_xor(s, 1); s += __shfl_xor(s, 2); s += __shfl_xor(s, 4); s += __shfl_xor(s, 8);
                pg[mt][r] = s;
            }
    }
    __syncthreads();                                  // ---- bar5 (GEMM2 reads done)
    #pragma unroll
    for (int mt = 0; mt < 2; ++mt)
        #pragma unroll
        for (int r = 0; r < 4; ++r) {
            int row = mt*16 + lg*4 + r;
            #pragma unroll
            for (int nt = 0; nt < 4; ++nt) {
                int col = wave*64 + nt*16 + lr;
                int idx = (row * H + col) ^ ((row & 7) << 3);
                sH[idx] = (__bf16)acc[mt][nt][r];
            }
        }
    if (lr == 0) {
        #pragma unroll
        for (int mt = 0; mt < 2; ++mt)
            #pragma unroll
            for (int r = 0; r < 4; ++r)
                sRedS[wave][mt*16 + lg*4 + r] = pg[mt][r];
    }
    __syncthreads();                                           // ---- bar6
    if (t < TM) {
        float z = sRedS[0][t] + sRedS[1][t] + sRedS[2][t] + sRedS[3][t] + bg[0];
        sGate[t] = 1.0f / (1.0f + __expf(-z));
    }
    __syncthreads();                                           // ---- bar7

    // ---------------- Phase 6: GEMM3  [32x256] x [256x128] ------------------
    f32x4 acc3[2][2];
    #pragma unroll
    for (int a = 0; a < 2; ++a)
        #pragma unroll
        for (int b = 0; b < 2; ++b) acc3[a][b] = f32x4{0.f,0.f,0.f,0.f};

    #pragma unroll
    for (int ks = 0; ks < 8; ++ks) {
        bf16x8 af[2];
        #pragma unroll
        for (int mt = 0; mt < 2; ++mt) {
            int row = mt*16 + lr;
            int idx = (row * H + ks*32 + lg*8) ^ ((row & 7) << 3);
            af[mt] = *reinterpret_cast<const bf16x8*>(&sH[idx]);
        }
        bf16x8 bv[2];
        #pragma unroll
        for (int nt = 0; nt < 2; ++nt) {
            int blk = (wave*2 + nt) * 8 + ks;        // 8 col tiles over N=128
            bv[nt] = *reinterpret_cast<const bf16x8*>(pwo + blk*512 + lane*8);
        }
        #pragma unroll
        for (int mt = 0; mt < 2; ++mt)
            #pragma unroll
            for (int nt = 0; nt < 2; ++nt)
                acc3[mt][nt] = __builtin_amdgcn_mfma_f32_16x16x32_bf16(af[mt], bv[nt], acc3[mt][nt], 0, 0, 0);
    }

    // ---------------- Phase 7: gate * (acc3 + bo) -> eout store OR scatter --
    {
        float bov[2];
        #pragma unroll
        for (int nt = 0; nt < 2; ++nt) bov[nt] = bo[wave*32 + nt*16 + lr];
        if (use_eout) {
            #pragma unroll
            for (int mt = 0; mt < 2; ++mt)
                #pragma unroll
                for (int r = 0; r < 4; ++r) {
                    int row = mt*16 + lg*4 + r;
                    int e = e0 + row;
                    if (e < E) {
                        float gt = sGate[row];
                        float* dst = eout + (size_t)e * D;
                        #pragma unroll
                        for (int nt = 0; nt < 2; ++nt) {
                            int col = wave*32 + nt*16 + lr;
                            dst[col] = (acc3[mt][nt][r] + bov[nt]) * gt;
                        }
                    }
                }
        } else {
            #pragma unroll
            for (int mt = 0; mt < 2; ++mt)
                #pragma unroll
                for (int r = 0; r < 4; ++r) {
                    int row = mt*16 + lg*4 + r;
                    if (e0 + row < E) {
                        int node = sIdx[row];
                        float gt = sGate[row];
                        float* dst = out + (size_t)node * D;
                        #pragma unroll
                        for (int nt = 0; nt < 2; ++nt) {
                            int col = wave*32 + nt*16 + lr;
                            float v = (acc3[mt][nt][r] + bov[nt]) * gt;
                            unsafeAtomicAdd(dst + col, v);
                        }
                    }
                }
        }
    }
}

// ---------------------------------------------------------------------------
extern "C" void kernel_launch(void* const* d_in, const int* in_sizes, int n_in,
                              void* d_out, int out_size, void* d_ws, size_t ws_size,
                              hipStream_t stream) {
    const float* edges = (const float*)d_in[0];
    const int*   eidx  = (const int*)d_in[1];
    // d_in[2] = num_nodes (scalar) — out_size already encodes N*D
    const float* ln1_g = (const float*)d_in[3];
    const float* ln1_b = (const float*)d_in[4];
    const float* w1    = (const float*)d_in[5];
    const float* b1    = (const float*)d_in[6];
    const float* ln2_g = (const float*)d_in[7];
    const float* ln2_b = (const float*)d_in[8];
    const float* w2    = (const float*)d_in[9];
    const float* b2    = (const float*)d_in[10];
    const float* wg    = (const float*)d_in[11];
    const float* bg    = (const float*)d_in[12];
    const float* wo    = (const float*)d_in[13];
    const float* bo    = (const float*)d_in[14];
    float* out = (float*)d_out;
    const int E = in_sizes[0] / D;
    const int N = out_size / D;

    // ws layout: eout (E*D f32) | pw (131072 bf16) | counts | offs | bsum | pos | order
    size_t eout_b  = (size_t)E * D * sizeof(float);          // 307.2 MB
    size_t pw_b    = 131072 * sizeof(__bf16);                // 256 KB
    size_t cnt_b   = (size_t)NSCAN * sizeof(int);            // 200 KB
    size_t offs_b  = (size_t)(NSCAN + 1) * sizeof(int);
    size_t bsum_b  = 64 * sizeof(int);
    size_t posord_b = (size_t)E * sizeof(int);               // 2.4 MB each
    size_t need = eout_b + pw_b + cnt_b + offs_b + bsum_b + 2 * posord_b;

    const int use_csr = (ws_size >= need) ? 1 : 0;

    if (use_csr) {
        float* eout  = (float*)d_ws;
        __bf16* pw   = (__bf16*)((char*)d_ws + eout_b);
        int* counts  = (int*)((char*)pw + pw_b);
        int* offs    = (int*)((char*)counts + cnt_b);
        int* bsum    = (int*)((char*)offs + offs_b);
        int* pos     = (int*)((char*)bsum + bsum_b);
        int* order   = (int*)((char*)pos + posord_b);

        pack_weights<<<512, 256, 0, stream>>>(w1, w2, wo, pw);
        csr_zero_counts<<<NSCAN / 256, 256, 0, stream>>>(counts);
        csr_hist<<<(E + 255) / 256, 256, 0, stream>>>(eidx, counts, pos, E);
        csr_scan1<<<49, 256, 0, stream>>>(counts, offs, bsum);
        csr_scan2<<<1, 64, 0, stream>>>(bsum);
        csr_scan3<<<NSCAN / 256, 256, 0, stream>>>(offs, bsum);
        csr_place<<<(E + 255) / 256, 256, 0, stream>>>(eidx, offs, pos, order, E);
        fused_edge_kernel<<<(E + TM - 1) / TM, THREADS, 0, stream>>>(
            edges, eidx, ln1_g, ln1_b, b1, ln2_g, ln2_b, b2, wg, bg, bo,
            pw, out, eout, 1, E);
        gather_kernel<<<(N + 3) / 4, 256, 0, stream>>>(eout, offs, order, out, N);
    } else {
        __bf16* pw = (__bf16*)d_ws;                          // 256 KB (always fits)
        pack_weights<<<512, 256, 0, stream>>>(w1, w2, wo, pw);
        int n4 = out_size / 4;
        zero_out_kernel<<<(n4 + 255) / 256, 256, 0, stream>>>((float4*)d_out, n4);
        fused_edge_kernel<<<(E + TM - 1) / TM, THREADS, 0, stream>>>(
            edges, eidx, ln1_g, ln1_b, b1, ln2_g, ln2_b, b2, wg, bg, bo,
            pw, out, nullptr, 0, E);
    }
}

// Round 10
// 472.723 us; speedup vs baseline: 1.3964x; 1.3964x over previous
//
#include <hip/hip_runtime.h>
#include <hip/hip_bf16.h>

typedef __bf16 bf16x8 __attribute__((ext_vector_type(8)));
typedef float f32x4 __attribute__((ext_vector_type(4)));

#define D 128
#define H 256
#define TM 32
#define THREADS 256
#define LN_EPS 1e-5f
#define NSCAN 50176            // 49 * 1024 >= num_nodes (50000)

// ---------------------------------------------------------------------------
// Pack w1 [128x256], w2 [256x256], wo [256x128] (f32 row-major, K x N) into
// bf16 MFMA-fragment-contiguous blocks:
//   out[b*512 + l*8 + i] = W[(k0 + (l>>4)*8 + i) * N + n0 + (l&15)]
//   block id: b = (n0/16)*(K/32) + (k0/32)
// ---------------------------------------------------------------------------
__global__ void pack_weights(const float* __restrict__ w1,
                             const float* __restrict__ w2,
                             const float* __restrict__ wo,
                             __bf16* __restrict__ pw) {
    int tid = blockIdx.x * blockDim.x + threadIdx.x;
    const float* W; int K, NN, local;
    if (tid < 32768)       { W = w1; K = 128; NN = 256; local = tid; }
    else if (tid < 98304)  { W = w2; K = 256; NN = 256; local = tid - 32768; }
    else if (tid < 131072) { W = wo; K = 256; NN = 128; local = tid - 98304; }
    else return;
    int b = local >> 9, within = local & 511;
    int l = within >> 3, i = within & 7;
    int nbk = K >> 5;
    int n0 = (b / nbk) << 4, k0 = (b % nbk) << 5;
    int k = k0 + ((l >> 4) << 3) + i;
    int n = n0 + (l & 15);
    pw[tid] = (__bf16)W[k * NN + n];
}

__global__ void zero_out_kernel(float4* __restrict__ out, int n4) {
    int i = blockIdx.x * blockDim.x + threadIdx.x;
    if (i < n4) out[i] = float4{0.f, 0.f, 0.f, 0.f};
}

// ------------------------------ CSR build ----------------------------------
__global__ void csr_zero_counts(int* __restrict__ counts) {
    int i = blockIdx.x * blockDim.x + threadIdx.x;
    if (i < NSCAN) counts[i] = 0;
}

__global__ void csr_hist(const int* __restrict__ eidx, int* __restrict__ counts,
                         int* __restrict__ pos, int E) {
    int e = blockIdx.x * blockDim.x + threadIdx.x;
    if (e < E) pos[e] = atomicAdd(&counts[eidx[e]], 1);
}

// 49 blocks x 256 threads x 4 elems: per-block exclusive scan + block totals
__global__ void csr_scan1(const int* __restrict__ counts, int* __restrict__ offs,
                          int* __restrict__ bsum) {
    __shared__ int wsum[4];
    int tid = threadIdx.x, blk = blockIdx.x;
    int base = blk * 1024 + tid * 4;
    int c0 = counts[base], c1 = counts[base+1], c2 = counts[base+2], c3 = counts[base+3];
    int tot = c0 + c1 + c2 + c3;
    int lane = tid & 63, wv = tid >> 6;
    int inc = tot;
    #pragma unroll
    for (int d = 1; d < 64; d <<= 1) {
        int v = __shfl_up(inc, d);
        if (lane >= d) inc += v;
    }
    if (lane == 63) wsum[wv] = inc;
    __syncthreads();
    int wbase = 0;
    for (int w = 0; w < wv; ++w) wbase += wsum[w];
    int excl = wbase + inc - tot;
    offs[base]   = excl;
    offs[base+1] = excl + c0;
    offs[base+2] = excl + c0 + c1;
    offs[base+3] = excl + c0 + c1 + c2;
    if (tid == 255) bsum[blk] = wbase + inc;
}

__global__ void csr_scan2(int* __restrict__ bsum) {   // in-place exclusive, 49 elems
    int l = threadIdx.x;                              // 64 threads
    int v = (l < 49) ? bsum[l] : 0;
    int inc = v;
    #pragma unroll
    for (int d = 1; d < 64; d <<= 1) {
        int u = __shfl_up(inc, d);
        if (l >= d) inc += u;
    }
    if (l < 49) bsum[l] = inc - v;
}

__global__ void csr_scan3(int* __restrict__ offs, const int* __restrict__ bsum) {
    int i = blockIdx.x * blockDim.x + threadIdx.x;
    if (i < NSCAN) offs[i] += bsum[i >> 10];
}

__global__ void csr_place(const int* __restrict__ eidx, const int* __restrict__ offs,
                          const int* __restrict__ pos, int* __restrict__ order, int E) {
    int e = blockIdx.x * blockDim.x + threadIdx.x;
    if (e < E) order[offs[eidx[e]] + pos[e]] = e;
}

// ------------------------------ gather -------------------------------------
// One wave per node: sum ~12 per-edge rows (512B coalesced reads), plain store.
// Zero atomics; fixed (CSR) order -> deterministic. Unroll-2: two independent
// order->row dependent-load chains in flight per iteration.
__global__ __launch_bounds__(256) void gather_kernel(
    const float* __restrict__ eout, const int* __restrict__ offs,
    const int* __restrict__ order, float* __restrict__ out, int N) {
    int wave = threadIdx.x >> 6, lane = threadIdx.x & 63;
    int n = blockIdx.x * 4 + wave;
    if (n >= N) return;
    int beg = offs[n];
    int end = offs[n + 1];          // offs[N] == E (pad counts are zero)
    float ax = 0.f, ay = 0.f;
    float bx = 0.f, by = 0.f;
    int j = beg;
    for (; j + 2 <= end; j += 2) {
        int e1 = order[j], e2 = order[j + 1];
        const float2 v1 = *reinterpret_cast<const float2*>(eout + (size_t)e1 * D + lane * 2);
        const float2 v2 = *reinterpret_cast<const float2*>(eout + (size_t)e2 * D + lane * 2);
        ax += v1.x; ay += v1.y;
        bx += v2.x; by += v2.y;
    }
    if (j < end) {
        int e = order[j];
        const float2 v = *reinterpret_cast<const float2*>(eout + (size_t)e * D + lane * 2);
        ax += v.x; ay += v.y;
    }
    *reinterpret_cast<float2*>(out + (size_t)n * D + lane * 2) = float2{ax + bx, ay + by};
}

// ---------------------------------------------------------------------------
// Fused edge MLP (R4/R8-proven structure: all-bf16 GEMMs, 7 barriers, TM=32).
// R9 lesson (== R2 lesson, now with receipts): (256,4) forced arch VGPR 84->64
// and spilled ~700MB/dispatch (FETCH 152->382MB, WRITE 300->768MB). The kernel
// structurally needs ~84 arch regs; 4 blocks/CU is unreachable without spill.
// (256,3) = 84 arch + 48 acc = 132 -> 3 blocks/CU, zero scratch, 438us (R8).
// LDS: sA (8 KB) aliases prefix of sH (16 KB); last sA read (GEMM1, pre-bar2)
// is 2 barriers before first sH write (post-bar3) — proven safe R4/R7/R8.
// ---------------------------------------------------------------------------
__global__ __launch_bounds__(THREADS, 3) void fused_edge_kernel(
    const float* __restrict__ edges, const int* __restrict__ eidx,
    const float* __restrict__ ln1_g, const float* __restrict__ ln1_b,
    const float* __restrict__ b1,
    const float* __restrict__ ln2_g, const float* __restrict__ ln2_b,
    const float* __restrict__ b2,
    const float* __restrict__ wg, const float* __restrict__ bg,
    const float* __restrict__ bo,
    const __bf16* __restrict__ pw,
    float* __restrict__ out, float* __restrict__ eout, int use_eout, int E)
{
    __shared__ __bf16 sH[TM * H];       // 16 KB; low 8 KB doubles as sA
    __shared__ float sRedS[4][TM];
    __shared__ float sRedQ[4][TM];
    __shared__ float sMu[TM], sRs[TM], sGate[TM];
    __shared__ int   sIdx[TM];
    __bf16* sA = sH;                    // alias (see header comment)

    const __bf16* pw1 = pw;             // 32768: w1 fragments
    const __bf16* pw2 = pw + 32768;     // 65536: w2 fragments
    const __bf16* pwo = pw + 98304;     // 32768: wo fragments

    const int t    = threadIdx.x;
    const int lane = t & 63;
    const int wave = t >> 6;
    const int lr   = lane & 15;         // tile row/col within 16
    const int lg   = lane >> 4;         // k-group / row-quad id
    const int e0   = blockIdx.x * TM;

    if (!use_eout && t < TM) sIdx[t] = (e0 + t < E) ? eidx[e0 + t] : 0;

    // ---------------- Phase 1: load edges + LN1 -> sA (bf16, swizzled) ------
    {
        const int row = t >> 3;          // 0..31
        const int c8  = t & 7;           // 16-col chunk of the row
        const int er  = min(e0 + row, E - 1);
        const float* src = edges + (size_t)er * D + c8 * 16;
        float x[16];
        #pragma unroll
        for (int i = 0; i < 4; ++i) {
            float4 v = reinterpret_cast<const float4*>(src)[i];
            x[i*4+0]=v.x; x[i*4+1]=v.y; x[i*4+2]=v.z; x[i*4+3]=v.w;
        }
        float s = 0.f, sq = 0.f;
        #pragma unroll
        for (int i = 0; i < 16; ++i) { s += x[i]; sq += x[i]*x[i]; }
        s  += __shfl_xor(s, 1);  s  += __shfl_xor(s, 2);  s  += __shfl_xor(s, 4);
        sq += __shfl_xor(sq, 1); sq += __shfl_xor(sq, 2); sq += __shfl_xor(sq, 4);
        const float mu  = s * (1.0f / D);
        const float var = sq * (1.0f / D) - mu * mu;
        const float rs  = rsqrtf(var + LN_EPS);
        const float4* g4 = reinterpret_cast<const float4*>(ln1_g + c8 * 16);
        const float4* b4 = reinterpret_cast<const float4*>(ln1_b + c8 * 16);
        #pragma unroll
        for (int i = 0; i < 2; ++i) {
            float4 ga = g4[2*i], gb = g4[2*i+1];
            float4 ba = b4[2*i], bb = b4[2*i+1];
            float gg[8] = {ga.x, ga.y, ga.z, ga.w, gb.x, gb.y, gb.z, gb.w};
            float bv[8] = {ba.x, ba.y, ba.z, ba.w, bb.x, bb.y, bb.z, bb.w};
            bf16x8 yv;
            #pragma unroll
            for (int j = 0; j < 8; ++j)
                yv[j] = (__bf16)((x[i*8+j] - mu) * rs * gg[j] + bv[j]);
            int idx = (row * D + c8*16 + i*8) ^ ((row & 7) << 3);
            *reinterpret_cast<bf16x8*>(&sA[idx]) = yv;
        }
    }
    __syncthreads();                                           // ---- bar1

    // ---------------- Phase 2: GEMM1  [32x128] x [128x256] ------------------
    f32x4 acc[2][4];
    #pragma unroll
    for (int a = 0; a < 2; ++a)
        #pragma unroll
        for (int b = 0; b < 4; ++b) acc[a][b] = f32x4{0.f,0.f,0.f,0.f};

    #pragma unroll
    for (int ks = 0; ks < 4; ++ks) {                 // k0 = ks*32
        bf16x8 af[2];
        #pragma unroll
        for (int mt = 0; mt < 2; ++mt) {
            int row = mt*16 + lr;
            int idx = (row * D + ks*32 + lg*8) ^ ((row & 7) << 3);
            af[mt] = *reinterpret_cast<const bf16x8*>(&sA[idx]);
        }
        bf16x8 bv[4];
        #pragma unroll
        for (int nt = 0; nt < 4; ++nt) {
            int blk = (wave*4 + nt) * 4 + ks;        // ctile*(128/32)+ks
            bv[nt] = *reinterpret_cast<const bf16x8*>(pw1 + blk*512 + lane*8);
        }
        #pragma unroll
        for (int mt = 0; mt < 2; ++mt)
            #pragma unroll
            for (int nt = 0; nt < 4; ++nt)
                acc[mt][nt] = __builtin_amdgcn_mfma_f32_16x16x32_bf16(af[mt], bv[nt], acc[mt][nt], 0, 0, 0);
    }

    // ---------------- Phase 3: +b1, ELU(expf-1), LN2 stats partials ---------
    float b1v[4];
    #pragma unroll
    for (int nt = 0; nt < 4; ++nt) b1v[nt] = b1[wave*64 + nt*16 + lr];
    {
        float ps[2][4], pq[2][4];                    // [mt][r]
        #pragma unroll
        for (int mt = 0; mt < 2; ++mt)
            #pragma unroll
            for (int r = 0; r < 4; ++r) { ps[mt][r] = 0.f; pq[mt][r] = 0.f; }
        #pragma unroll
        for (int mt = 0; mt < 2; ++mt)
            #pragma unroll
            for (int nt = 0; nt < 4; ++nt)
                #pragma unroll
                for (int r = 0; r < 4; ++r) {
                    float x = acc[mt][nt][r] + b1v[nt];
                    x = x > 0.f ? x : (__expf(x) - 1.0f);    // ELU
                    acc[mt][nt][r] = x;
                    ps[mt][r] += x;
                    pq[mt][r] += x * x;
                }
        #pragma unroll
        for (int mt = 0; mt < 2; ++mt)
            #pragma unroll
            for (int r = 0; r < 4; ++r) {
                float s = ps[mt][r], q = pq[mt][r];
                s += __shfl_xor(s, 1); s += __shfl_xor(s, 2); s += __shfl_xor(s, 4); s += __shfl_xor(s, 8);
                q += __shfl_xor(q, 1); q += __shfl_xor(q, 2); q += __shfl_xor(q, 4); q += __shfl_xor(q, 8);
                if (lr == 0) {
                    int row = mt*16 + lg*4 + r;
                    sRedS[wave][row] = s;
                    sRedQ[wave][row] = q;
                }
            }
    }
    __syncthreads();                                           // ---- bar2
    if (t < TM) {
        float S = sRedS[0][t] + sRedS[1][t] + sRedS[2][t] + sRedS[3][t];
        float Q = sRedQ[0][t] + sRedQ[1][t] + sRedQ[2][t] + sRedQ[3][t];
        float mu  = S * (1.0f / H);
        float var = Q * (1.0f / H) - mu * mu;
        sMu[t] = mu;
        sRs[t] = rsqrtf(var + LN_EPS);
    }
    __syncthreads();                                           // ---- bar3

    // write LN2 output (bf16, swizzled) into sH (overwrites dead sA alias)
    {
        float g2v[4], bt2[4];
        #pragma unroll
        for (int nt = 0; nt < 4; ++nt) {
            g2v[nt] = ln2_g[wave*64 + nt*16 + lr];
            bt2[nt] = ln2_b[wave*64 + nt*16 + lr];
        }
        #pragma unroll
        for (int mt = 0; mt < 2; ++mt)
            #pragma unroll
            for (int r = 0; r < 4; ++r) {
                int row = mt*16 + lg*4 + r;
                float mu = sMu[row], rs = sRs[row];
                #pragma unroll
                for (int nt = 0; nt < 4; ++nt) {
                    int col = wave*64 + nt*16 + lr;
                    float h = (acc[mt][nt][r] - mu) * rs * g2v[nt] + bt2[nt];
                    int idx = (row * H + col) ^ ((row & 7) << 3);
                    sH[idx] = (__bf16)h;
                }
            }
    }
    __syncthreads();                                           // ---- bar4

    // ---------------- Phase 4: GEMM2  [32x256] x [256x256] ------------------
    #pragma unroll
    for (int a = 0; a < 2; ++a)
        #pragma unroll
        for (int b = 0; b < 4; ++b) acc[a][b] = f32x4{0.f,0.f,0.f,0.f};

    #pragma unroll
    for (int ks = 0; ks < 8; ++ks) {
        bf16x8 af[2];
        #pragma unroll
        for (int mt = 0; mt < 2; ++mt) {
            int row = mt*16 + lr;
            int idx = (row * H + ks*32 + lg*8) ^ ((row & 7) << 3);
            af[mt] = *reinterpret_cast<const bf16x8*>(&sH[idx]);
        }
        bf16x8 bv[4];
        #pragma unroll
        for (int nt = 0; nt < 4; ++nt) {
            int blk = (wave*4 + nt) * 8 + ks;        // ctile*(256/32)+ks
            bv[nt] = *reinterpret_cast<const bf16x8*>(pw2 + blk*512 + lane*8);
        }
        #pragma unroll
        for (int mt = 0; mt < 2; ++mt)
            #pragma unroll
            for (int nt = 0; nt < 4; ++nt)
                acc[mt][nt] = __builtin_amdgcn_mfma_f32_16x16x32_bf16(af[mt], bv[nt], acc[mt][nt], 0, 0, 0);
    }

    // ---------------- Phase 5: +b2, gate partials ---------------------------
    float pg[2][4];
    {
        float b2v[4], wgv[4];
        #pragma unroll
        for (int nt = 0; nt < 4; ++nt) {
            b2v[nt] = b2[wave*64 + nt*16 + lr];
            wgv[nt] = wg[wave*64 + nt*16 + lr];
        }
        #pragma unroll
        for (int mt = 0; mt < 2; ++mt)
            #pragma unroll
            for (int r = 0; r < 4; ++r) pg[mt][r] = 0.f;
        #pragma unroll
        for (int mt = 0; mt < 2; ++mt)
            #pragma unroll
            for (int nt = 0; nt < 4; ++nt)
                #pragma unroll
                for (int r = 0; r < 4; ++r) {
                    float h2 = acc[mt][nt][r] + b2v[nt];
                    acc[mt][nt][r] = h2;
                    pg[mt][r] += h2 * wgv[nt];
                }
        #pragma unroll
        for (int mt = 0; mt < 2; ++mt)
            #pragma unroll
            for (int r = 0; r < 4; ++r) {
                float s = pg[mt][r];
                s += __shfl_xor(s, 1); s += __shfl_xor(s, 2); s += __shfl_xor(s, 4); s += __shfl_xor(s, 8);
                pg[mt][r] = s;
            }
    }
    __syncthreads();                                  // ---- bar5 (GEMM2 reads done)
    #pragma unroll
    for (int mt = 0; mt < 2; ++mt)
        #pragma unroll
        for (int r = 0; r < 4; ++r) {
            int row = mt*16 + lg*4 + r;
            #pragma unroll
            for (int nt = 0; nt < 4; ++nt) {
                int col = wave*64 + nt*16 + lr;
                int idx = (row * H + col) ^ ((row & 7) << 3);
                sH[idx] = (__bf16)acc[mt][nt][r];
            }
        }
    if (lr == 0) {
        #pragma unroll
        for (int mt = 0; mt < 2; ++mt)
            #pragma unroll
            for (int r = 0; r < 4; ++r)
                sRedS[wave][mt*16 + lg*4 + r] = pg[mt][r];
    }
    __syncthreads();                                           // ---- bar6
    if (t < TM) {
        float z = sRedS[0][t] + sRedS[1][t] + sRedS[2][t] + sRedS[3][t] + bg[0];
        sGate[t] = 1.0f / (1.0f + __expf(-z));
    }
    __syncthreads();                                           // ---- bar7

    // ---------------- Phase 6: GEMM3  [32x256] x [256x128] ------------------
    f32x4 acc3[2][2];
    #pragma unroll
    for (int a = 0; a < 2; ++a)
        #pragma unroll
        for (int b = 0; b < 2; ++b) acc3[a][b] = f32x4{0.f,0.f,0.f,0.f};

    #pragma unroll
    for (int ks = 0; ks < 8; ++ks) {
        bf16x8 af[2];
        #pragma unroll
        for (int mt = 0; mt < 2; ++mt) {
            int row = mt*16 + lr;
            int idx = (row * H + ks*32 + lg*8) ^ ((row & 7) << 3);
            af[mt] = *reinterpret_cast<const bf16x8*>(&sH[idx]);
        }
        bf16x8 bv[2];
        #pragma unroll
        for (int nt = 0; nt < 2; ++nt) {
            int blk = (wave*2 + nt) * 8 + ks;        // 8 col tiles over N=128
            bv[nt] = *reinterpret_cast<const bf16x8*>(pwo + blk*512 + lane*8);
        }
        #pragma unroll
        for (int mt = 0; mt < 2; ++mt)
            #pragma unroll
            for (int nt = 0; nt < 2; ++nt)
                acc3[mt][nt] = __builtin_amdgcn_mfma_f32_16x16x32_bf16(af[mt], bv[nt], acc3[mt][nt], 0, 0, 0);
    }

    // ---------------- Phase 7: gate * (acc3 + bo) -> eout store OR scatter --
    {
        float bov[2];
        #pragma unroll
        for (int nt = 0; nt < 2; ++nt) bov[nt] = bo[wave*32 + nt*16 + lr];
        if (use_eout) {
            #pragma unroll
            for (int mt = 0; mt < 2; ++mt)
                #pragma unroll
                for (int r = 0; r < 4; ++r) {
                    int row = mt*16 + lg*4 + r;
                    int e = e0 + row;
                    if (e < E) {
                        float gt = sGate[row];
                        float* dst = eout + (size_t)e * D;
                        #pragma unroll
                        for (int nt = 0; nt < 2; ++nt) {
                            int col = wave*32 + nt*16 + lr;
                            dst[col] = (acc3[mt][nt][r] + bov[nt]) * gt;
                        }
                    }
                }
        } else {
            #pragma unroll
            for (int mt = 0; mt < 2; ++mt)
                #pragma unroll
                for (int r = 0; r < 4; ++r) {
                    int row = mt*16 + lg*4 + r;
                    if (e0 + row < E) {
                        int node = sIdx[row];
                        float gt = sGate[row];
                        float* dst = out + (size_t)node * D;
                        #pragma unroll
                        for (int nt = 0; nt < 2; ++nt) {
                            int col = wave*32 + nt*16 + lr;
                            float v = (acc3[mt][nt][r] + bov[nt]) * gt;
                            unsafeAtomicAdd(dst + col, v);
                        }
                    }
                }
        }
    }
}

// ---------------------------------------------------------------------------
extern "C" void kernel_launch(void* const* d_in, const int* in_sizes, int n_in,
                              void* d_out, int out_size, void* d_ws, size_t ws_size,
                              hipStream_t stream) {
    const float* edges = (const float*)d_in[0];
    const int*   eidx  = (const int*)d_in[1];
    // d_in[2] = num_nodes (scalar) — out_size already encodes N*D
    const float* ln1_g = (const float*)d_in[3];
    const float* ln1_b = (const float*)d_in[4];
    const float* w1    = (const float*)d_in[5];
    const float* b1    = (const float*)d_in[6];
    const float* ln2_g = (const float*)d_in[7];
    const float* ln2_b = (const float*)d_in[8];
    const float* w2    = (const float*)d_in[9];
    const float* b2    = (const float*)d_in[10];
    const float* wg    = (const float*)d_in[11];
    const float* bg    = (const float*)d_in[12];
    const float* wo    = (const float*)d_in[13];
    const float* bo    = (const float*)d_in[14];
    float* out = (float*)d_out;
    const int E = in_sizes[0] / D;
    const int N = out_size / D;

    // ws layout: eout (E*D f32) | pw (131072 bf16) | counts | offs | bsum | pos | order
    size_t eout_b  = (size_t)E * D * sizeof(float);          // 307.2 MB
    size_t pw_b    = 131072 * sizeof(__bf16);                // 256 KB
    size_t cnt_b   = (size_t)NSCAN * sizeof(int);            // 200 KB
    size_t offs_b  = (size_t)(NSCAN + 1) * sizeof(int);
    size_t bsum_b  = 64 * sizeof(int);
    size_t posord_b = (size_t)E * sizeof(int);               // 2.4 MB each
    size_t need = eout_b + pw_b + cnt_b + offs_b + bsum_b + 2 * posord_b;

    const int use_csr = (ws_size >= need) ? 1 : 0;

    if (use_csr) {
        float* eout  = (float*)d_ws;
        __bf16* pw   = (__bf16*)((char*)d_ws + eout_b);
        int* counts  = (int*)((char*)pw + pw_b);
        int* offs    = (int*)((char*)counts + cnt_b);
        int* bsum    = (int*)((char*)offs + offs_b);
        int* pos     = (int*)((char*)bsum + bsum_b);
        int* order   = (int*)((char*)pos + posord_b);

        pack_weights<<<512, 256, 0, stream>>>(w1, w2, wo, pw);
        csr_zero_counts<<<NSCAN / 256, 256, 0, stream>>>(counts);
        csr_hist<<<(E + 255) / 256, 256, 0, stream>>>(eidx, counts, pos, E);
        csr_scan1<<<49, 256, 0, stream>>>(counts, offs, bsum);
        csr_scan2<<<1, 64, 0, stream>>>(bsum);
        csr_scan3<<<NSCAN / 256, 256, 0, stream>>>(offs, bsum);
        csr_place<<<(E + 255) / 256, 256, 0, stream>>>(eidx, offs, pos, order, E);
        fused_edge_kernel<<<(E + TM - 1) / TM, THREADS, 0, stream>>>(
            edges, eidx, ln1_g, ln1_b, b1, ln2_g, ln2_b, b2, wg, bg, bo,
            pw, out, eout, 1, E);
        gather_kernel<<<(N + 3) / 4, 256, 0, stream>>>(eout, offs, order, out, N);
    } else {
        __bf16* pw = (__bf16*)d_ws;                          // 256 KB (always fits)
        pack_weights<<<512, 256, 0, stream>>>(w1, w2, wo, pw);
        int n4 = out_size / 4;
        zero_out_kernel<<<(n4 + 255) / 256, 256, 0, stream>>>((float4*)d_out, n4);
        fused_edge_kernel<<<(E + TM - 1) / TM, THREADS, 0, stream>>>(
            edges, eidx, ln1_g, ln1_b, b1, ln2_g, ln2_b, b2, wg, bg, bo,
            pw, out, nullptr, 0, E);
    }
}